// Round 3
// baseline (962.065 us; speedup 1.0000x reference)
//
#include <hip/hip_runtime.h>
#include <hip/hip_bf16.h>

// CTC forward loss, T=4096, C=8192, L=512 -> S=1025 states.
// Phase A (ctc_emit): per-row log2-softmax + gather emissions at the 1025
//   extended-target states, normalized per row (max = 1, offset c_t), bf16.
// Phase B (ctc_scan1w): SINGLE-WAVE linear-domain alpha recursion with
//   PER-LANE block-floating-point scale (int omega per lane, 16 states/lane).
//   Boundary value converted by ldexp(omega_l - omega_{l-1}); rescale every
//   8 steps per lane (no cross-lane reduction). Fixes the global-scale
//   fp32 flush/refill bias seen in rounds 0-1.

#define T_STEPS 4096
#define N_CLASSES 8192
#define S_TOT 1025
#define PSTRIDE 1026              // elements per P row (pad to even)
#define PROWB (PSTRIDE * 2)       // 2052 bytes per bf16 row
#define INV_LN2 1.4426950408889634f
#define LN2F 0.6931471805599453f

static __device__ __forceinline__ float wredMax(float v) {
#pragma unroll
  for (int d = 32; d >= 1; d >>= 1) v = fmaxf(v, __shfl_xor(v, d, 64));
  return v;
}
static __device__ __forceinline__ float wredSum(float v) {
#pragma unroll
  for (int d = 32; d >= 1; d >>= 1) v += __shfl_xor(v, d, 64);
  return v;
}

// ---------------- Phase A: emissions ----------------
__global__ __launch_bounds__(256) void ctc_emit(const float* __restrict__ logits,
                                                const int* __restrict__ targets,
                                                __hip_bfloat16* __restrict__ P,
                                                float* __restrict__ cvec) {
  __shared__ __align__(16) float row[N_CLASSES];
  __shared__ float red[4];
  const int t = blockIdx.x;
  const int tid = threadIdx.x;
  const int lane = tid & 63, wid = tid >> 6;
  const float4* src = (const float4*)(logits + (size_t)t * N_CLASSES);

  float4 v[8];
  float lmax = -3.0e38f;
#pragma unroll
  for (int k = 0; k < 8; ++k) {
    v[k] = src[tid + 256 * k];
    ((float4*)row)[tid + 256 * k] = v[k];
    lmax = fmaxf(lmax, fmaxf(fmaxf(v[k].x, v[k].y), fmaxf(v[k].z, v[k].w)));
  }
  lmax = wredMax(lmax);
  if (lane == 0) red[wid] = lmax;
  __syncthreads();
  const float rowmax = fmaxf(fmaxf(red[0], red[1]), fmaxf(red[2], red[3]));
  const float m2 = rowmax * INV_LN2;

  float acc = 0.f;
#pragma unroll
  for (int k = 0; k < 8; ++k) {
    acc += exp2f(fmaf(v[k].x, INV_LN2, -m2));
    acc += exp2f(fmaf(v[k].y, INV_LN2, -m2));
    acc += exp2f(fmaf(v[k].z, INV_LN2, -m2));
    acc += exp2f(fmaf(v[k].w, INV_LN2, -m2));
  }
  acc = wredSum(acc);
  __syncthreads();
  if (lane == 0) red[wid] = acc;
  __syncthreads();
  const float Z = red[0] + red[1] + red[2] + red[3];
  const float denom2 = m2 + log2f(Z);   // lp2[c] = x[c]/ln2 - denom2

  float e2v[5];
  float gmax = -3.0e38f;
#pragma unroll
  for (int k = 0; k < 5; ++k) {
    int s = tid + 256 * k;
    if (s < S_TOT) {
      int cls = (s & 1) ? targets[(s - 1) >> 1] : 0;   // even states = blank(0)
      float e2 = fmaf(row[cls], INV_LN2, -denom2);
      e2v[k] = e2;
      gmax = fmaxf(gmax, e2);
    }
  }
  gmax = wredMax(gmax);
  __syncthreads();
  if (lane == 0) red[wid] = gmax;
  __syncthreads();
  const float ct = fmaxf(fmaxf(red[0], red[1]), fmaxf(red[2], red[3]));

  __hip_bfloat16* Prow = P + (size_t)t * PSTRIDE;
#pragma unroll
  for (int k = 0; k < 5; ++k) {
    int s = tid + 256 * k;
    if (s < S_TOT) Prow[s] = __float2bfloat16(exp2f(e2v[k] - ct));
  }
  if (tid == 0) cvec[t] = ct;
}

// ---------------- Phase B: single-wave scan, per-lane scale ----------------
__global__ __launch_bounds__(64, 1) void ctc_scan1w(const char* __restrict__ Pb,
                                                    const float* __restrict__ cvec,
                                                    const int* __restrict__ targets,
                                                    float* __restrict__ out) {
  const int lane = threadIdx.x;

  // allow-skip flags for odd local states j=2k+1 (global s=16*lane+2k+1,
  // label idx = 8*lane + k): label != blank && label != previous label
  float al[8];
#pragma unroll
  for (int k = 0; k < 8; ++k) {
    int li = 8 * lane + k;
    int c = targets[li];
    int cm1 = (li == 0) ? -1 : targets[li - 1];
    al[k] = (c != 0 && c != cm1) ? 1.0f : 0.0f;
  }

  // sum of per-row log2 normalization offsets
  float sc = 0.f;
  for (int i = lane; i < T_STEPS; i += 64) sc += cvec[i];
  sc = wredSum(sc);

  // state registers
  float a[16], b[16], a16 = 0.f, b16;
#pragma unroll
  for (int j = 0; j < 16; ++j) a[j] = 0.f;
  if (lane == 0) {
    unsigned int pv0 = *(const unsigned int*)(Pb);
    a[0] = __uint_as_float((pv0 & 0xFFFFu) << 16);
    a[1] = __uint_as_float(pv0 & 0xFFFF0000u);
  }
  int omega = 0;   // per-lane: stored = true * 2^omega
  int wprev = 0;   // upstream lane's omega (sampled after each rescale)
  int wd = 0;      // omega - wprev, conversion shift for incoming boundary

  // prefetch ring, depth 4: rows t..t+3. 32 B/lane + broadcast u16 (state 1024)
  uint4 q0[4], q1[4];
  unsigned short qe[4];
  const char* myp = Pb + 32 * lane;
#pragma unroll
  for (int j = 0; j < 4; ++j) {
    const char* rp = myp + (size_t)(1 + j) * PROWB;
    q0[j] = *(const uint4*)(rp);
    q1[j] = *(const uint4*)(rp + 16);
    qe[j] = *(const unsigned short*)(Pb + (size_t)(1 + j) * PROWB + 2048);
  }

  int t = 1;

#define UNPK_LO(u) __uint_as_float((u) << 16)
#define UNPK_HI(u) __uint_as_float((u) & 0xFFFF0000u)

#define SSTEP(A, A16, B, B16)                                                  \
  {                                                                            \
    const int slot = (t - 1) & 3;                                              \
    const uint4 x0 = q0[slot];                                                 \
    const uint4 x1 = q1[slot];                                                 \
    const unsigned int xe = qe[slot];                                          \
    {                                                                          \
      const char* rp = myp + (size_t)(t + 4) * PROWB;                          \
      q0[slot] = *(const uint4*)(rp);                                          \
      q1[slot] = *(const uint4*)(rp + 16);                                     \
      qe[slot] = *(const unsigned short*)(Pb + (size_t)(t + 4) * PROWB + 2048);\
    }                                                                          \
    float La15 = __shfl_up(A[15], 1, 64);                                      \
    La15 = (lane == 0) ? 0.f : ldexpf(La15, wd);                               \
    B[0] = (A[0] + La15) * UNPK_LO(x0.x);                                      \
    B[1] = fmaf(al[0], La15, A[1] + A[0]) * UNPK_HI(x0.x);                     \
    B[2] = (A[2] + A[1]) * UNPK_LO(x0.y);                                      \
    B[3] = fmaf(al[1], A[1], A[3] + A[2]) * UNPK_HI(x0.y);                     \
    B[4] = (A[4] + A[3]) * UNPK_LO(x0.z);                                      \
    B[5] = fmaf(al[2], A[3], A[5] + A[4]) * UNPK_HI(x0.z);                     \
    B[6] = (A[6] + A[5]) * UNPK_LO(x0.w);                                      \
    B[7] = fmaf(al[3], A[5], A[7] + A[6]) * UNPK_HI(x0.w);                     \
    B[8] = (A[8] + A[7]) * UNPK_LO(x1.x);                                      \
    B[9] = fmaf(al[4], A[7], A[9] + A[8]) * UNPK_HI(x1.x);                     \
    B[10] = (A[10] + A[9]) * UNPK_LO(x1.y);                                    \
    B[11] = fmaf(al[5], A[9], A[11] + A[10]) * UNPK_HI(x1.y);                  \
    B[12] = (A[12] + A[11]) * UNPK_LO(x1.z);                                   \
    B[13] = fmaf(al[6], A[11], A[13] + A[12]) * UNPK_HI(x1.z);                 \
    B[14] = (A[14] + A[13]) * UNPK_LO(x1.w);                                   \
    B[15] = fmaf(al[7], A[13], A[15] + A[14]) * UNPK_HI(x1.w);                 \
    B16 = (lane == 63) ? (A16 + A[15]) * UNPK_LO(xe) : 0.f;                    \
    ++t;                                                                       \
  }

  // per-lane rescale: set own max's exponent to 127 (value in [1,2)).
  // Empty lanes (pre-frontier) adopt the upstream scale so first inflow
  // converts with small delta.
#define RESCALE(A, A16)                                                        \
  {                                                                            \
    float m = 0.f;                                                             \
    _Pragma("unroll") for (int j = 0; j < 16; ++j) m = fmaxf(m, A[j]);         \
    if (lane == 63) m = fmaxf(m, A16);                                         \
    if (m > 0.f) {                                                             \
      int e = (int)((__float_as_uint(m) >> 23) & 255u);                        \
      int shift = 127 - e;                                                     \
      _Pragma("unroll") for (int j = 0; j < 16; ++j) A[j] = ldexpf(A[j], shift); \
      A16 = ldexpf(A16, shift);                                                \
      omega += shift;                                                          \
    } else {                                                                   \
      omega = wprev;                                                           \
    }                                                                          \
    wprev = __shfl_up(omega, 1, 64);                                           \
    wd = omega - wprev;                                                        \
  }

  for (int g = 0; g < 511; ++g) {   // steps t = 1 .. 4088
    SSTEP(a, a16, b, b16);
    SSTEP(b, b16, a, a16);
    SSTEP(a, a16, b, b16);
    SSTEP(b, b16, a, a16);
    SSTEP(a, a16, b, b16);
    SSTEP(b, b16, a, a16);
    SSTEP(a, a16, b, b16);
    SSTEP(b, b16, a, a16);
    RESCALE(a, a16);
  }
  // steps t = 4089 .. 4095 (7 steps; result ends in b)
  SSTEP(a, a16, b, b16);
  SSTEP(b, b16, a, a16);
  SSTEP(a, a16, b, b16);
  SSTEP(b, b16, a, a16);
  SSTEP(a, a16, b, b16);
  SSTEP(b, b16, a, a16);
  SSTEP(a, a16, b, b16);

  if (lane == 63) {
    // states 1023 (b[15]) and 1024 (b16), lane-63 scale: 2^(sc - omega)
    float tot = b[15] + b16;
    out[0] = -LN2F * (log2f(tot) + sc - (float)omega);
  }
}

extern "C" void kernel_launch(void* const* d_in, const int* in_sizes, int n_in,
                              void* d_out, int out_size, void* d_ws, size_t ws_size,
                              hipStream_t stream) {
  (void)in_sizes; (void)n_in; (void)out_size; (void)ws_size;
  const float* logits = (const float*)d_in[0];
  const int* targets = (const int*)d_in[1];
  // ws layout: P bf16 [4096 x 1026] (8,404,992 B) | 64 rows slack | cvec f32[4096]
  char* ws = (char*)d_ws;
  __hip_bfloat16* P = (__hip_bfloat16*)ws;
  float* cvec = (float*)(ws + (size_t)T_STEPS * PROWB + 64 * PROWB);

  ctc_emit<<<dim3(T_STEPS), dim3(256), 0, stream>>>(logits, targets, P, cvec);
  ctc_scan1w<<<dim3(1), dim3(64), 0, stream>>>((const char*)P, cvec, targets,
                                               (float*)d_out);
}